// Round 1
// baseline (1535.519 us; speedup 1.0000x reference)
//
#include <hip/hip_runtime.h>

// MPNN_edge_sparse_ogb — round 0 baseline
// Pipeline: init_z (z = concat(x,degrees)) -> edge_pass (atomicAdd relu(h[src]+ef) into z)
//        -> mlp (out = relu(z@W1+b1)@W2 + b2), all fp32.
// ws layout: z [N*128] f32 (25.6 MB).

constexpr int DIN  = 96;
constexpr int DDEG = 32;
constexpr int D    = 128;   // concat feature dim
constexpr int DH   = 256;
constexpr int DUP  = 128;

// ---------------------------------------------------------------- init: z = concat(x, degrees)
__global__ __launch_bounds__(256) void init_z_kernel(
    const float* __restrict__ x, const float* __restrict__ deg,
    float* __restrict__ z, int N) {
    int t = blockIdx.x * 256 + threadIdx.x;
    int total = N * 32;                 // 32 float4 chunks per node
    if (t >= total) return;
    int n = t >> 5, c = t & 31;
    float4 v;
    if (c < 24) v = *reinterpret_cast<const float4*>(&x[n * DIN + c * 4]);
    else        v = *reinterpret_cast<const float4*>(&deg[n * DDEG + (c - 24) * 4]);
    *reinterpret_cast<float4*>(&z[n * D + c * 4]) = v;
}

// ---------------------------------------------------------------- edge pass: scatter-atomic
__global__ __launch_bounds__(256) void edge_pass_kernel(
    const float* __restrict__ x, const float* __restrict__ deg,
    const float* __restrict__ ef, const int* __restrict__ ei,
    float* __restrict__ z, int N, int E) {
    long long t = (long long)blockIdx.x * 256 + threadIdx.x;
    long long total = (long long)E * 32;
    if (t >= total) return;
    int e = (int)(t >> 5), c = (int)(t & 31);
    int src = ei[e];
    int dst = ei[E + e];
    float4 fv = *reinterpret_cast<const float4*>(&ef[(long long)e * D + c * 4]);
    float4 hv;
    if (c < 24) hv = *reinterpret_cast<const float4*>(&x[src * DIN + c * 4]);
    else        hv = *reinterpret_cast<const float4*>(&deg[src * DDEG + (c - 24) * 4]);
    float* zp = &z[(long long)dst * D + c * 4];
    float v0 = fmaxf(fv.x + hv.x, 0.0f);
    float v1 = fmaxf(fv.y + hv.y, 0.0f);
    float v2 = fmaxf(fv.z + hv.z, 0.0f);
    float v3 = fmaxf(fv.w + hv.w, 0.0f);
#if defined(__gfx90a__) || defined(__gfx940__) || defined(__gfx941__) || defined(__gfx942__) || defined(__gfx950__)
    unsafeAtomicAdd(zp + 0, v0);
    unsafeAtomicAdd(zp + 1, v1);
    unsafeAtomicAdd(zp + 2, v2);
    unsafeAtomicAdd(zp + 3, v3);
#else
    atomicAdd(zp + 0, v0);
    atomicAdd(zp + 1, v1);
    atomicAdd(zp + 2, v2);
    atomicAdd(zp + 3, v3);
#endif
}

// ---------------------------------------------------------------- fused MLP: 16 nodes / block
__global__ __launch_bounds__(256) void mlp_kernel(
    const float* __restrict__ z,
    const float* __restrict__ W1, const float* __restrict__ b1,
    const float* __restrict__ W2, const float* __restrict__ b2,
    float* __restrict__ out, int N) {
    __shared__ float zs[16 * 128];   // 8 KB
    __shared__ float us[16 * 256];   // 16 KB
    const int tid = threadIdx.x;
    const int n0  = blockIdx.x * 16;

    // ---- load z tile (2048 floats = 512 float4; 2 per thread), guarded
    {
        const float4* zg = reinterpret_cast<const float4*>(z) + (long long)n0 * 32;
        float4* zl = reinterpret_cast<float4*>(zs);
        int r0 = n0 + (tid >> 5);          // rows n0 .. n0+7
        if (r0 < N)      zl[tid]       = zg[tid];
        int r1 = n0 + 8 + (tid >> 5);      // rows n0+8 .. n0+15
        if (r1 < N)      zl[256 + tid] = zg[256 + tid];
    }
    __syncthreads();

    // ---- phase 2: u = relu(z @ W1 + b1), thread = 4 nodes x 4 cols
    {
        const int tn = tid >> 6;       // 0..3  -> nodes tn*4 .. tn*4+3
        const int tj = tid & 63;       // 0..63 -> cols  tj*4 .. tj*4+3
        float acc[4][4];
#pragma unroll
        for (int jj = 0; jj < 4; ++jj) {
            float b = b1[tj * 4 + jj];
#pragma unroll
            for (int i = 0; i < 4; ++i) acc[i][jj] = b;
        }
#pragma unroll 4
        for (int k = 0; k < 128; k += 4) {
            alignas(16) float zk[4][4];
            alignas(16) float w[4][4];
#pragma unroll
            for (int i = 0; i < 4; ++i)
                *reinterpret_cast<float4*>(&zk[i][0]) =
                    *reinterpret_cast<const float4*>(&zs[(tn * 4 + i) * 128 + k]);
#pragma unroll
            for (int kk = 0; kk < 4; ++kk)
                *reinterpret_cast<float4*>(&w[kk][0]) =
                    *reinterpret_cast<const float4*>(&W1[(k + kk) * 256 + tj * 4]);
#pragma unroll
            for (int i = 0; i < 4; ++i)
#pragma unroll
                for (int kk = 0; kk < 4; ++kk)
#pragma unroll
                    for (int jj = 0; jj < 4; ++jj)
                        acc[i][jj] += zk[i][kk] * w[kk][jj];
        }
#pragma unroll
        for (int i = 0; i < 4; ++i) {
            float4 v;
            v.x = fmaxf(acc[i][0], 0.0f);
            v.y = fmaxf(acc[i][1], 0.0f);
            v.z = fmaxf(acc[i][2], 0.0f);
            v.w = fmaxf(acc[i][3], 0.0f);
            *reinterpret_cast<float4*>(&us[(tn * 4 + i) * 256 + tj * 4]) = v;
        }
    }
    __syncthreads();

    // ---- phase 3: out = u @ W2 + b2, thread = 4 nodes x 2 cols
    {
        const int tn2 = tid >> 6;      // 0..3  -> nodes tn2*4 .. +3
        const int tj2 = tid & 63;      // 0..63 -> cols tj2*2, tj2*2+1
        float acc2[4][2];
#pragma unroll
        for (int jj = 0; jj < 2; ++jj) {
            float b = b2[tj2 * 2 + jj];
#pragma unroll
            for (int i = 0; i < 4; ++i) acc2[i][jj] = b;
        }
#pragma unroll 4
        for (int k = 0; k < 256; k += 4) {
            alignas(16) float u4[4][4];
            alignas(8)  float w2[4][2];
#pragma unroll
            for (int i = 0; i < 4; ++i)
                *reinterpret_cast<float4*>(&u4[i][0]) =
                    *reinterpret_cast<const float4*>(&us[(tn2 * 4 + i) * 256 + k]);
#pragma unroll
            for (int kk = 0; kk < 4; ++kk)
                *reinterpret_cast<float2*>(&w2[kk][0]) =
                    *reinterpret_cast<const float2*>(&W2[(k + kk) * 128 + tj2 * 2]);
#pragma unroll
            for (int i = 0; i < 4; ++i)
#pragma unroll
                for (int kk = 0; kk < 4; ++kk)
#pragma unroll
                    for (int jj = 0; jj < 2; ++jj)
                        acc2[i][jj] += u4[i][kk] * w2[kk][jj];
        }
#pragma unroll
        for (int i = 0; i < 4; ++i) {
            int row = n0 + tn2 * 4 + i;
            if (row < N) {
                float2 v;
                v.x = acc2[i][0];
                v.y = acc2[i][1];
                *reinterpret_cast<float2*>(&out[(long long)row * DUP + tj2 * 2]) = v;
            }
        }
    }
}

// ---------------------------------------------------------------- launch
extern "C" void kernel_launch(void* const* d_in, const int* in_sizes, int n_in,
                              void* d_out, int out_size, void* d_ws, size_t ws_size,
                              hipStream_t stream) {
    const float* x   = (const float*)d_in[0];
    const float* dg  = (const float*)d_in[1];
    const float* ef  = (const float*)d_in[2];
    const float* W1  = (const float*)d_in[3];
    const float* b1  = (const float*)d_in[4];
    const float* W2  = (const float*)d_in[5];
    const float* b2  = (const float*)d_in[6];
    const int*   ei  = (const int*)d_in[7];
    float* out = (float*)d_out;

    const int N = in_sizes[0] / DIN;       // 50000
    const int E = in_sizes[7] / 2;         // 800000

    float* z = (float*)d_ws;               // N*128 f32 = 25.6 MB

    int initBlocks = (N * 32 + 255) / 256;
    init_z_kernel<<<initBlocks, 256, 0, stream>>>(x, dg, z, N);

    long long tE = (long long)E * 32;
    int edgeBlocks = (int)((tE + 255) / 256);
    edge_pass_kernel<<<edgeBlocks, 256, 0, stream>>>(x, dg, ef, ei, z, N, E);

    int mlpBlocks = (N + 15) / 16;
    mlp_kernel<<<mlpBlocks, 256, 0, stream>>>(z, W1, b1, W2, b2, out, N);
}

// Round 2
// 503.599 us; speedup vs baseline: 3.0491x; 3.0491x over previous
//
#include <hip/hip_runtime.h>

// MPNN_edge_sparse_ogb — round 1: CSR-gather instead of scatter-atomics.
// Pipeline: count -> scan -> fill (CSR by dst) -> gather (z = h + sum relu(h[src]+ef))
//        -> mlp (out = relu(z@W1+b1)@W2 + b2), all fp32.
// ws layout: z [N*128] f32 | counts [N] i32 | offsets [N+1] i32 | cursor [N] i32 | eids [E] i32

constexpr int DIN  = 96;
constexpr int DDEG = 32;
constexpr int D    = 128;   // concat feature dim
constexpr int DH   = 256;
constexpr int DUP  = 128;

// ---------------------------------------------------------------- 1. count in-degrees
__global__ __launch_bounds__(256) void count_kernel(
    const int* __restrict__ ei, int* __restrict__ counts, int N, int E) {
    int e = blockIdx.x * 256 + threadIdx.x;
    if (e >= E) return;
    int dst = ei[E + e];
    atomicAdd(&counts[dst], 1);
}

// ---------------------------------------------------------------- 2. exclusive scan (1 block)
__global__ __launch_bounds__(1024) void scan_kernel(
    const int* __restrict__ counts, int* __restrict__ offsets,
    int* __restrict__ cursor, int N) {
    __shared__ int buf[1024];
    __shared__ int carry;
    const int tid = threadIdx.x;
    if (tid == 0) { carry = 0; offsets[0] = 0; }
    __syncthreads();
    for (int base = 0; base < N; base += 1024) {
        int i = base + tid;
        int v = (i < N) ? counts[i] : 0;
        buf[tid] = v;
        __syncthreads();
        // Hillis-Steele inclusive scan over 1024
        for (int off = 1; off < 1024; off <<= 1) {
            int t = (tid >= off) ? buf[tid - off] : 0;
            __syncthreads();
            buf[tid] += t;
            __syncthreads();
        }
        int incl = buf[tid] + carry;
        if (i < N) {
            offsets[i + 1] = incl;       // inclusive = offsets of i+1
            cursor[i]      = incl - v;   // exclusive prefix = start
        }
        __syncthreads();
        if (tid == 1023) carry = incl;
        __syncthreads();
    }
}

// ---------------------------------------------------------------- 3. fill edge-id lists
__global__ __launch_bounds__(256) void fill_kernel(
    const int* __restrict__ ei, int* __restrict__ cursor,
    int* __restrict__ eids, int E) {
    int e = blockIdx.x * 256 + threadIdx.x;
    if (e >= E) return;
    int dst = ei[E + e];
    int pos = atomicAdd(&cursor[dst], 1);
    eids[pos] = e;
}

// ---------------------------------------------------------------- 4. gather: z = h + sum relu(h[src]+ef)
// 32 lanes per node (one float4 chunk each), 8 nodes per 256-block.
__global__ __launch_bounds__(256) void gather_kernel(
    const float* __restrict__ x, const float* __restrict__ deg,
    const float* __restrict__ ef, const int* __restrict__ ei,
    const int* __restrict__ offsets, const int* __restrict__ eids,
    float* __restrict__ z, int N, int E) {
    const int node = blockIdx.x * 8 + (threadIdx.x >> 5);
    if (node >= N) return;
    const int c = threadIdx.x & 31;   // float4 chunk 0..31

    float4 h;
    if (c < 24) h = *reinterpret_cast<const float4*>(&x[(size_t)node * DIN + c * 4]);
    else        h = *reinterpret_cast<const float4*>(&deg[(size_t)node * DDEG + (c - 24) * 4]);

    float4 acc = make_float4(0.f, 0.f, 0.f, 0.f);
    const int pBeg = offsets[node], pEnd = offsets[node + 1];
    for (int p = pBeg; p < pEnd; ++p) {
        int e   = eids[p];
        int src = ei[e];
        float4 fv = *reinterpret_cast<const float4*>(&ef[(size_t)e * D + c * 4]);
        float4 hs;
        if (c < 24) hs = *reinterpret_cast<const float4*>(&x[(size_t)src * DIN + c * 4]);
        else        hs = *reinterpret_cast<const float4*>(&deg[(size_t)src * DDEG + (c - 24) * 4]);
        acc.x += fmaxf(fv.x + hs.x, 0.f);
        acc.y += fmaxf(fv.y + hs.y, 0.f);
        acc.z += fmaxf(fv.z + hs.z, 0.f);
        acc.w += fmaxf(fv.w + hs.w, 0.f);
    }
    float4 zv;
    zv.x = h.x + acc.x; zv.y = h.y + acc.y; zv.z = h.z + acc.z; zv.w = h.w + acc.w;
    *reinterpret_cast<float4*>(&z[(size_t)node * D + c * 4]) = zv;
}

// ---------------------------------------------------------------- 5. fused MLP: 16 nodes / block
__global__ __launch_bounds__(256) void mlp_kernel(
    const float* __restrict__ z,
    const float* __restrict__ W1, const float* __restrict__ b1,
    const float* __restrict__ W2, const float* __restrict__ b2,
    float* __restrict__ out, int N) {
    __shared__ float zs[16 * 128];   // 8 KB
    __shared__ float us[16 * 256];   // 16 KB
    const int tid = threadIdx.x;
    const int n0  = blockIdx.x * 16;

    {
        const float4* zg = reinterpret_cast<const float4*>(z) + (long long)n0 * 32;
        float4* zl = reinterpret_cast<float4*>(zs);
        int r0 = n0 + (tid >> 5);
        if (r0 < N)      zl[tid]       = zg[tid];
        int r1 = n0 + 8 + (tid >> 5);
        if (r1 < N)      zl[256 + tid] = zg[256 + tid];
    }
    __syncthreads();

    {
        const int tn = tid >> 6;
        const int tj = tid & 63;
        float acc[4][4];
#pragma unroll
        for (int jj = 0; jj < 4; ++jj) {
            float b = b1[tj * 4 + jj];
#pragma unroll
            for (int i = 0; i < 4; ++i) acc[i][jj] = b;
        }
#pragma unroll 4
        for (int k = 0; k < 128; k += 4) {
            alignas(16) float zk[4][4];
            alignas(16) float w[4][4];
#pragma unroll
            for (int i = 0; i < 4; ++i)
                *reinterpret_cast<float4*>(&zk[i][0]) =
                    *reinterpret_cast<const float4*>(&zs[(tn * 4 + i) * 128 + k]);
#pragma unroll
            for (int kk = 0; kk < 4; ++kk)
                *reinterpret_cast<float4*>(&w[kk][0]) =
                    *reinterpret_cast<const float4*>(&W1[(k + kk) * 256 + tj * 4]);
#pragma unroll
            for (int i = 0; i < 4; ++i)
#pragma unroll
                for (int kk = 0; kk < 4; ++kk)
#pragma unroll
                    for (int jj = 0; jj < 4; ++jj)
                        acc[i][jj] += zk[i][kk] * w[kk][jj];
        }
#pragma unroll
        for (int i = 0; i < 4; ++i) {
            float4 v;
            v.x = fmaxf(acc[i][0], 0.0f);
            v.y = fmaxf(acc[i][1], 0.0f);
            v.z = fmaxf(acc[i][2], 0.0f);
            v.w = fmaxf(acc[i][3], 0.0f);
            *reinterpret_cast<float4*>(&us[(tn * 4 + i) * 256 + tj * 4]) = v;
        }
    }
    __syncthreads();

    {
        const int tn2 = tid >> 6;
        const int tj2 = tid & 63;
        float acc2[4][2];
#pragma unroll
        for (int jj = 0; jj < 2; ++jj) {
            float b = b2[tj2 * 2 + jj];
#pragma unroll
            for (int i = 0; i < 4; ++i) acc2[i][jj] = b;
        }
#pragma unroll 4
        for (int k = 0; k < 256; k += 4) {
            alignas(16) float u4[4][4];
            alignas(8)  float w2[4][2];
#pragma unroll
            for (int i = 0; i < 4; ++i)
                *reinterpret_cast<float4*>(&u4[i][0]) =
                    *reinterpret_cast<const float4*>(&us[(tn2 * 4 + i) * 256 + k]);
#pragma unroll
            for (int kk = 0; kk < 4; ++kk)
                *reinterpret_cast<float2*>(&w2[kk][0]) =
                    *reinterpret_cast<const float2*>(&W2[(k + kk) * 128 + tj2 * 2]);
#pragma unroll
            for (int i = 0; i < 4; ++i)
#pragma unroll
                for (int kk = 0; kk < 4; ++kk)
#pragma unroll
                    for (int jj = 0; jj < 2; ++jj)
                        acc2[i][jj] += u4[i][kk] * w2[kk][jj];
        }
#pragma unroll
        for (int i = 0; i < 4; ++i) {
            int row = n0 + tn2 * 4 + i;
            if (row < N) {
                float2 v;
                v.x = acc2[i][0];
                v.y = acc2[i][1];
                *reinterpret_cast<float2*>(&out[(long long)row * DUP + tj2 * 2]) = v;
            }
        }
    }
}

// ---------------------------------------------------------------- launch
extern "C" void kernel_launch(void* const* d_in, const int* in_sizes, int n_in,
                              void* d_out, int out_size, void* d_ws, size_t ws_size,
                              hipStream_t stream) {
    const float* x   = (const float*)d_in[0];
    const float* dg  = (const float*)d_in[1];
    const float* ef  = (const float*)d_in[2];
    const float* W1  = (const float*)d_in[3];
    const float* b1  = (const float*)d_in[4];
    const float* W2  = (const float*)d_in[5];
    const float* b2  = (const float*)d_in[6];
    const int*   ei  = (const int*)d_in[7];
    float* out = (float*)d_out;

    const int N = in_sizes[0] / DIN;       // 50000
    const int E = in_sizes[7] / 2;         // 800000

    // ws carve-up (16B aligned)
    char* w = (char*)d_ws;
    float* z       = (float*)w;                     w += (size_t)N * D * 4;      // 25.6 MB
    int*   counts  = (int*)w;                       w += (size_t)N * 4;
    int*   offsets = (int*)w;                       w += (size_t)(N + 1) * 4 + 12;
    int*   cursor  = (int*)w;                       w += (size_t)N * 4;
    int*   eids    = (int*)w;                       w += (size_t)E * 4;

    hipMemsetAsync(counts, 0, (size_t)N * 4, stream);

    int eb = (E + 255) / 256;
    count_kernel<<<eb, 256, 0, stream>>>(ei, counts, N, E);
    scan_kernel<<<1, 1024, 0, stream>>>(counts, offsets, cursor, N);
    fill_kernel<<<eb, 256, 0, stream>>>(ei, cursor, eids, E);

    int gb = (N + 7) / 8;
    gather_kernel<<<gb, 256, 0, stream>>>(x, dg, ef, ei, offsets, eids, z, N, E);

    int mlpBlocks = (N + 15) / 16;
    mlp_kernel<<<mlpBlocks, 256, 0, stream>>>(z, W1, b1, W2, b2, out, N);
}

// Round 3
// 291.542 us; speedup vs baseline: 5.2669x; 1.7274x over previous
//
#include <hip/hip_runtime.h>

// MPNN_edge_sparse_ogb — round 2:
//  - hierarchical scan (3 small kernels) replaces single-block scan
//  - gather emits z as bf16; MLP rewritten with mfma_f32_16x16x32_bf16
// ws: zb[N*128]bf16 | counts[N] | offsets[N+1] | cursor[N] | eids[E] | blockSums/Base | w1p | w2p

constexpr int DIN  = 96;
constexpr int DDEG = 32;
constexpr int D    = 128;
constexpr int DH   = 256;
constexpr int DUP  = 128;

typedef short bf16x8 __attribute__((ext_vector_type(8)));
typedef float f32x4  __attribute__((ext_vector_type(4)));

static __device__ __forceinline__ ushort f2bf(float f) {
    unsigned u = __float_as_uint(f);
    unsigned r = (u + 0x7fff + ((u >> 16) & 1)) >> 16;   // RNE
    return (ushort)r;
}

static __device__ __forceinline__ int waveInclScan(int v, int lane) {
#pragma unroll
    for (int off = 1; off < 64; off <<= 1) {
        int t = __shfl_up(v, off, 64);
        if (lane >= off) v += t;
    }
    return v;
}

// ---------------------------------------------------------------- 1. count in-degrees
__global__ __launch_bounds__(256) void count_kernel(
    const int* __restrict__ ei, int* __restrict__ counts, int N, int E) {
    int e = blockIdx.x * 256 + threadIdx.x;
    if (e >= E) return;
    atomicAdd(&counts[ei[E + e]], 1);
}

// ---------------------------------------------------------------- 2a. per-1024-block sums
__global__ __launch_bounds__(256) void scan_partial_kernel(
    const int* __restrict__ counts, int* __restrict__ blockSums, int N) {
    const int tid = threadIdx.x;
    int base = blockIdx.x * 1024 + tid * 4;
    int4 c = make_int4(0, 0, 0, 0);
    if (base + 3 < N) c = *reinterpret_cast<const int4*>(&counts[base]);
    else if (base < N) {
        c.x = counts[base];
        if (base + 1 < N) c.y = counts[base + 1];
        if (base + 2 < N) c.z = counts[base + 2];
    }
    int s = c.x + c.y + c.z + c.w;
#pragma unroll
    for (int off = 32; off; off >>= 1) s += __shfl_xor(s, off, 64);
    __shared__ int wsum[4];
    if ((tid & 63) == 0) wsum[tid >> 6] = s;
    __syncthreads();
    if (tid == 0) blockSums[blockIdx.x] = wsum[0] + wsum[1] + wsum[2] + wsum[3];
}

// ---------------------------------------------------------------- 2b. scan 49 block sums
__global__ __launch_bounds__(64) void scan_base_kernel(
    const int* __restrict__ blockSums, int* __restrict__ blockBase, int nb) {
    int l = threadIdx.x;
    int orig = (l < nb) ? blockSums[l] : 0;
    int incl = waveInclScan(orig, l);
    if (l < nb) blockBase[l] = incl - orig;
}

// ---------------------------------------------------------------- 2c. final scan -> offsets/cursor
__global__ __launch_bounds__(256) void scan_final_kernel(
    const int* __restrict__ counts, const int* __restrict__ blockBase,
    int* __restrict__ offsets, int* __restrict__ cursor, int N, int E) {
    const int tid = threadIdx.x, lane = tid & 63, wave = tid >> 6;
    int base = blockIdx.x * 1024 + tid * 4;
    int4 c = make_int4(0, 0, 0, 0);
    if (base + 3 < N) c = *reinterpret_cast<const int4*>(&counts[base]);
    else if (base < N) {
        c.x = counts[base];
        if (base + 1 < N) c.y = counts[base + 1];
        if (base + 2 < N) c.z = counts[base + 2];
    }
    int s = c.x + c.y + c.z + c.w;
    int incl = waveInclScan(s, lane);
    __shared__ int wsum[4];
    if (lane == 63) wsum[wave] = incl;
    __syncthreads();
    int wb = 0;
#pragma unroll
    for (int w = 0; w < 4; ++w)
        if (w < wave) wb += wsum[w];
    int ex = blockBase[blockIdx.x] + wb + (incl - s);
    if (base < N)     { offsets[base]     = ex; cursor[base]     = ex; } ex += c.x;
    if (base + 1 < N) { offsets[base + 1] = ex; cursor[base + 1] = ex; } ex += c.y;
    if (base + 2 < N) { offsets[base + 2] = ex; cursor[base + 2] = ex; } ex += c.z;
    if (base + 3 < N) { offsets[base + 3] = ex; cursor[base + 3] = ex; }
    if (blockIdx.x == 0 && tid == 0) offsets[N] = E;
}

// ---------------------------------------------------------------- 3. fill edge-id lists
__global__ __launch_bounds__(256) void fill_kernel(
    const int* __restrict__ ei, int* __restrict__ cursor,
    int* __restrict__ eids, int E) {
    int e = blockIdx.x * 256 + threadIdx.x;
    if (e >= E) return;
    int pos = atomicAdd(&cursor[ei[E + e]], 1);
    eids[pos] = e;
}

// ---------------------------------------------------------------- 4. gather: zb = bf16(h + sum relu(h[src]+ef))
__global__ __launch_bounds__(256) void gather_kernel(
    const float* __restrict__ x, const float* __restrict__ deg,
    const float* __restrict__ ef, const int* __restrict__ ei,
    const int* __restrict__ offsets, const int* __restrict__ eids,
    ushort* __restrict__ zb, int N, int E) {
    const int node = blockIdx.x * 8 + (threadIdx.x >> 5);
    if (node >= N) return;
    const int c = threadIdx.x & 31;

    float4 h;
    if (c < 24) h = *reinterpret_cast<const float4*>(&x[(size_t)node * DIN + c * 4]);
    else        h = *reinterpret_cast<const float4*>(&deg[(size_t)node * DDEG + (c - 24) * 4]);

    float4 acc = make_float4(0.f, 0.f, 0.f, 0.f);
    const int pBeg = offsets[node], pEnd = offsets[node + 1];
    int e_nxt = 0, src_nxt = 0;
    if (pBeg < pEnd) { e_nxt = eids[pBeg]; src_nxt = ei[e_nxt]; }
    for (int p = pBeg; p < pEnd; ++p) {
        int e = e_nxt, src = src_nxt;
        if (p + 1 < pEnd) { e_nxt = eids[p + 1]; src_nxt = ei[e_nxt]; }
        float4 fv = *reinterpret_cast<const float4*>(&ef[(size_t)e * D + c * 4]);
        float4 hs;
        if (c < 24) hs = *reinterpret_cast<const float4*>(&x[(size_t)src * DIN + c * 4]);
        else        hs = *reinterpret_cast<const float4*>(&deg[(size_t)src * DDEG + (c - 24) * 4]);
        acc.x += fmaxf(fv.x + hs.x, 0.f);
        acc.y += fmaxf(fv.y + hs.y, 0.f);
        acc.z += fmaxf(fv.z + hs.z, 0.f);
        acc.w += fmaxf(fv.w + hs.w, 0.f);
    }
    ushort4 o;
    o.x = f2bf(h.x + acc.x);
    o.y = f2bf(h.y + acc.y);
    o.z = f2bf(h.z + acc.z);
    o.w = f2bf(h.w + acc.w);
    *reinterpret_cast<ushort4*>(&zb[(size_t)node * D + c * 4]) = o;
}

// ---------------------------------------------------------------- 5. pack weights into MFMA fragment order
// w1p[((kb*16+nb)*64+l)*8+j] = bf16(W1[kb*32+(l>>4)*8+j][nb*16+(l&15)])   kb<4, nb<16
// w2p[((kb*8 +nb)*64+l)*8+j] = bf16(W2[kb*32+(l>>4)*8+j][nb*16+(l&15)])   kb<8, nb<8
__global__ __launch_bounds__(256) void pack_w_kernel(
    const float* __restrict__ W1, const float* __restrict__ W2,
    ushort* __restrict__ w1p, ushort* __restrict__ w2p) {
    int idx = blockIdx.x * 256 + threadIdx.x;
    if (idx >= 32768) return;
    {
        int j = idx & 7, l = (idx >> 3) & 63, nb = (idx >> 9) & 15, kb = idx >> 13;
        int k = kb * 32 + (l >> 4) * 8 + j, n = nb * 16 + (l & 15);
        w1p[idx] = f2bf(W1[k * DH + n]);
    }
    {
        int j = idx & 7, l = (idx >> 3) & 63, nb = (idx >> 9) & 7, kb = idx >> 12;
        int k = kb * 32 + (l >> 4) * 8 + j, n = nb * 16 + (l & 15);
        w2p[idx] = f2bf(W2[k * DUP + n]);
    }
}

// ---------------------------------------------------------------- 6. MFMA MLP: 64 nodes/block, 16/wave
__global__ __launch_bounds__(256) void mlp_mfma_kernel(
    const ushort* __restrict__ zb,
    const ushort* __restrict__ w1p, const float* __restrict__ b1,
    const ushort* __restrict__ w2p, const float* __restrict__ b2,
    float* __restrict__ out, int N) {
    __shared__ ushort u_lds[4][16][DH + 8];   // +8 bf16 pad = 16B, keeps b128 alignment
    const int tid = threadIdx.x;
    const int wave = tid >> 6, lane = tid & 63;
    const int m0 = blockIdx.x * 64 + wave * 16;
    const int lr = lane & 15, lg = lane >> 4;

    // A1 fragments: z rows, 4 K-chunks of 32
    bf16x8 a1[4];
    int rowA = m0 + lr; if (rowA > N - 1) rowA = N - 1;
    const ushort* zrow = &zb[(size_t)rowA * D + lg * 8];
#pragma unroll
    for (int kb = 0; kb < 4; ++kb)
        a1[kb] = *reinterpret_cast<const bf16x8*>(zrow + kb * 32);

    // GEMM1: u = relu(z @ W1 + b1) -> LDS (bf16)
#pragma unroll
    for (int nb = 0; nb < 16; ++nb) {
        f32x4 c = {0.f, 0.f, 0.f, 0.f};
#pragma unroll
        for (int kb = 0; kb < 4; ++kb) {
            bf16x8 b = *reinterpret_cast<const bf16x8*>(&w1p[((kb * 16 + nb) * 64 + lane) * 8]);
            c = __builtin_amdgcn_mfma_f32_16x16x32_bf16(a1[kb], b, c, 0, 0, 0);
        }
        float bias = b1[nb * 16 + lr];
#pragma unroll
        for (int r = 0; r < 4; ++r) {
            float v = fmaxf(c[r] + bias, 0.f);
            u_lds[wave][lg * 4 + r][nb * 16 + lr] = f2bf(v);
        }
    }
    __syncthreads();

    // A2 fragments from LDS
    bf16x8 a2[8];
#pragma unroll
    for (int kb = 0; kb < 8; ++kb)
        a2[kb] = *reinterpret_cast<const bf16x8*>(&u_lds[wave][lr][kb * 32 + lg * 8]);

    // GEMM2: out = u @ W2 + b2
#pragma unroll
    for (int nb = 0; nb < 8; ++nb) {
        f32x4 c = {0.f, 0.f, 0.f, 0.f};
#pragma unroll
        for (int kb = 0; kb < 8; ++kb) {
            bf16x8 b = *reinterpret_cast<const bf16x8*>(&w2p[((kb * 8 + nb) * 64 + lane) * 8]);
            c = __builtin_amdgcn_mfma_f32_16x16x32_bf16(a2[kb], b, c, 0, 0, 0);
        }
        float bias = b2[nb * 16 + lr];
#pragma unroll
        for (int r = 0; r < 4; ++r) {
            int row = m0 + lg * 4 + r;
            if (row < N) out[(size_t)row * DUP + nb * 16 + lr] = c[r] + bias;
        }
    }
}

// ---------------------------------------------------------------- launch
extern "C" void kernel_launch(void* const* d_in, const int* in_sizes, int n_in,
                              void* d_out, int out_size, void* d_ws, size_t ws_size,
                              hipStream_t stream) {
    const float* x   = (const float*)d_in[0];
    const float* dg  = (const float*)d_in[1];
    const float* ef  = (const float*)d_in[2];
    const float* W1  = (const float*)d_in[3];
    const float* b1  = (const float*)d_in[4];
    const float* W2  = (const float*)d_in[5];
    const float* b2  = (const float*)d_in[6];
    const int*   ei  = (const int*)d_in[7];
    float* out = (float*)d_out;

    const int N = in_sizes[0] / DIN;       // 50000
    const int E = in_sizes[7] / 2;         // 800000

    auto align16 = [](size_t v) { return (v + 15) & ~(size_t)15; };
    char* w = (char*)d_ws;
    ushort* zb      = (ushort*)w;  w += align16((size_t)N * D * 2);
    int*   counts   = (int*)w;     w += align16((size_t)N * 4);
    int*   offsets  = (int*)w;     w += align16((size_t)(N + 1) * 4);
    int*   cursor   = (int*)w;     w += align16((size_t)N * 4);
    int*   eids     = (int*)w;     w += align16((size_t)E * 4);
    int*   blockSums= (int*)w;     w += align16(64 * 4);
    int*   blockBase= (int*)w;     w += align16(64 * 4);
    ushort* w1p     = (ushort*)w;  w += align16((size_t)D * DH * 2);
    ushort* w2p     = (ushort*)w;  w += align16((size_t)DH * DUP * 2);

    hipMemsetAsync(counts, 0, (size_t)N * 4, stream);

    const int eb = (E + 255) / 256;
    const int nbScan = (N + 1023) / 1024;   // 49

    count_kernel<<<eb, 256, 0, stream>>>(ei, counts, N, E);
    scan_partial_kernel<<<nbScan, 256, 0, stream>>>(counts, blockSums, N);
    scan_base_kernel<<<1, 64, 0, stream>>>(blockSums, blockBase, nbScan);
    scan_final_kernel<<<nbScan, 256, 0, stream>>>(counts, blockBase, offsets, cursor, N, E);
    fill_kernel<<<eb, 256, 0, stream>>>(ei, cursor, eids, E);

    gather_kernel<<<(N + 7) / 8, 256, 0, stream>>>(x, dg, ef, ei, offsets, eids, zb, N, E);

    pack_w_kernel<<<128, 256, 0, stream>>>(W1, W2, w1p, w2p);
    mlp_mfma_kernel<<<(N + 63) / 64, 256, 0, stream>>>(zb, w1p, b1, w2p, b2, out, N);
}

// Round 4
// 249.177 us; speedup vs baseline: 6.1624x; 1.1700x over previous
//
#include <hip/hip_runtime.h>

// MPNN_edge_sparse_ogb — round 3:
//  - gather v2: wave/node, 2 edges/iter + unroll2 (4 ef rows in flight), int2 CSR
//    payload {e,src} (no ei indirection), bf16 packed h, nontemporal ef stream.
// ws: zb[N*128]bf16 | hp[N*128]bf16 | counts | offsets | cursor | eids2[E]int2 | sums | w1p | w2p

constexpr int DIN  = 96;
constexpr int DDEG = 32;
constexpr int D    = 128;
constexpr int DH   = 256;
constexpr int DUP  = 128;

typedef short bf16x8 __attribute__((ext_vector_type(8)));
typedef float f32x4  __attribute__((ext_vector_type(4)));

static __device__ __forceinline__ ushort f2bf(float f) {
    unsigned u = __float_as_uint(f);
    unsigned r = (u + 0x7fff + ((u >> 16) & 1)) >> 16;   // RNE
    return (ushort)r;
}
static __device__ __forceinline__ float4 bf4_to_f4(ushort4 u) {
    float4 r;
    r.x = __uint_as_float((unsigned)u.x << 16);
    r.y = __uint_as_float((unsigned)u.y << 16);
    r.z = __uint_as_float((unsigned)u.z << 16);
    r.w = __uint_as_float((unsigned)u.w << 16);
    return r;
}

static __device__ __forceinline__ int waveInclScan(int v, int lane) {
#pragma unroll
    for (int off = 1; off < 64; off <<= 1) {
        int t = __shfl_up(v, off, 64);
        if (lane >= off) v += t;
    }
    return v;
}

// ---------------------------------------------------------------- 0. pack h = bf16(concat(x,deg))
__global__ __launch_bounds__(256) void init_h_kernel(
    const float* __restrict__ x, const float* __restrict__ deg,
    ushort* __restrict__ hp, int N) {
    int t = blockIdx.x * 256 + threadIdx.x;
    if (t >= N * 32) return;
    int n = t >> 5, c = t & 31;
    float4 v;
    if (c < 24) v = *reinterpret_cast<const float4*>(&x[(size_t)n * DIN + c * 4]);
    else        v = *reinterpret_cast<const float4*>(&deg[(size_t)n * DDEG + (c - 24) * 4]);
    ushort4 o;
    o.x = f2bf(v.x); o.y = f2bf(v.y); o.z = f2bf(v.z); o.w = f2bf(v.w);
    *reinterpret_cast<ushort4*>(&hp[(size_t)n * D + c * 4]) = o;
}

// ---------------------------------------------------------------- 1. count in-degrees
__global__ __launch_bounds__(256) void count_kernel(
    const int* __restrict__ ei, int* __restrict__ counts, int N, int E) {
    int e = blockIdx.x * 256 + threadIdx.x;
    if (e >= E) return;
    atomicAdd(&counts[ei[E + e]], 1);
}

// ---------------------------------------------------------------- 2a. per-1024-block sums
__global__ __launch_bounds__(256) void scan_partial_kernel(
    const int* __restrict__ counts, int* __restrict__ blockSums, int N) {
    const int tid = threadIdx.x;
    int base = blockIdx.x * 1024 + tid * 4;
    int4 c = make_int4(0, 0, 0, 0);
    if (base + 3 < N) c = *reinterpret_cast<const int4*>(&counts[base]);
    else if (base < N) {
        c.x = counts[base];
        if (base + 1 < N) c.y = counts[base + 1];
        if (base + 2 < N) c.z = counts[base + 2];
    }
    int s = c.x + c.y + c.z + c.w;
#pragma unroll
    for (int off = 32; off; off >>= 1) s += __shfl_xor(s, off, 64);
    __shared__ int wsum[4];
    if ((tid & 63) == 0) wsum[tid >> 6] = s;
    __syncthreads();
    if (tid == 0) blockSums[blockIdx.x] = wsum[0] + wsum[1] + wsum[2] + wsum[3];
}

// ---------------------------------------------------------------- 2b. scan block sums (<=64)
__global__ __launch_bounds__(64) void scan_base_kernel(
    const int* __restrict__ blockSums, int* __restrict__ blockBase, int nb) {
    int l = threadIdx.x;
    int orig = (l < nb) ? blockSums[l] : 0;
    int incl = waveInclScan(orig, l);
    if (l < nb) blockBase[l] = incl - orig;
}

// ---------------------------------------------------------------- 2c. final scan -> offsets/cursor
__global__ __launch_bounds__(256) void scan_final_kernel(
    const int* __restrict__ counts, const int* __restrict__ blockBase,
    int* __restrict__ offsets, int* __restrict__ cursor, int N, int E) {
    const int tid = threadIdx.x, lane = tid & 63, wave = tid >> 6;
    int base = blockIdx.x * 1024 + tid * 4;
    int4 c = make_int4(0, 0, 0, 0);
    if (base + 3 < N) c = *reinterpret_cast<const int4*>(&counts[base]);
    else if (base < N) {
        c.x = counts[base];
        if (base + 1 < N) c.y = counts[base + 1];
        if (base + 2 < N) c.z = counts[base + 2];
    }
    int s = c.x + c.y + c.z + c.w;
    int incl = waveInclScan(s, lane);
    __shared__ int wsum[4];
    if (lane == 63) wsum[wave] = incl;
    __syncthreads();
    int wb = 0;
#pragma unroll
    for (int w = 0; w < 4; ++w)
        if (w < wave) wb += wsum[w];
    int ex = blockBase[blockIdx.x] + wb + (incl - s);
    if (base < N)     { offsets[base]     = ex; cursor[base]     = ex; } ex += c.x;
    if (base + 1 < N) { offsets[base + 1] = ex; cursor[base + 1] = ex; } ex += c.y;
    if (base + 2 < N) { offsets[base + 2] = ex; cursor[base + 2] = ex; } ex += c.z;
    if (base + 3 < N) { offsets[base + 3] = ex; cursor[base + 3] = ex; }
    if (blockIdx.x == 0 && tid == 0) offsets[N] = E;
}

// ---------------------------------------------------------------- 3. fill CSR payload {e, src}
__global__ __launch_bounds__(256) void fill_kernel(
    const int* __restrict__ ei, int* __restrict__ cursor,
    int2* __restrict__ eids2, int E) {
    int e = blockIdx.x * 256 + threadIdx.x;
    if (e >= E) return;
    int src = ei[e];
    int dst = ei[E + e];
    int pos = atomicAdd(&cursor[dst], 1);
    eids2[pos] = make_int2(e, src);
}

// ---------------------------------------------------------------- 4. gather: zb = bf16(h + sum relu(h[src]+ef))
// one wave per node; half-waves take alternating CSR slots; unroll 2.
__global__ __launch_bounds__(256) void gather_kernel(
    const ushort* __restrict__ hp, const float* __restrict__ ef,
    const int* __restrict__ offsets, const int2* __restrict__ eids2,
    ushort* __restrict__ zb, int N) {
    const int wave = threadIdx.x >> 6, lane = threadIdx.x & 63;
    const int node = blockIdx.x * 4 + wave;
    if (node >= N) return;
    const int c = lane & 31;       // float4 chunk
    const int eh = lane >> 5;      // edge-slot half

    float4 h = bf4_to_f4(*reinterpret_cast<const ushort4*>(&hp[(size_t)node * D + c * 4]));

    float4 acc = make_float4(0.f, 0.f, 0.f, 0.f);
    const int pBeg = offsets[node], pEnd = offsets[node + 1];
    int p = pBeg + eh;
    for (; p + 2 < pEnd; p += 4) {
        int2 ea = eids2[p];
        int2 eb = eids2[p + 2];
        f32x4 f0 = __builtin_nontemporal_load(
            reinterpret_cast<const f32x4*>(&ef[(size_t)ea.x * D + c * 4]));
        f32x4 f1 = __builtin_nontemporal_load(
            reinterpret_cast<const f32x4*>(&ef[(size_t)eb.x * D + c * 4]));
        float4 h0 = bf4_to_f4(*reinterpret_cast<const ushort4*>(&hp[(size_t)ea.y * D + c * 4]));
        float4 h1 = bf4_to_f4(*reinterpret_cast<const ushort4*>(&hp[(size_t)eb.y * D + c * 4]));
        acc.x += fmaxf(f0[0] + h0.x, 0.f) + fmaxf(f1[0] + h1.x, 0.f);
        acc.y += fmaxf(f0[1] + h0.y, 0.f) + fmaxf(f1[1] + h1.y, 0.f);
        acc.z += fmaxf(f0[2] + h0.z, 0.f) + fmaxf(f1[2] + h1.z, 0.f);
        acc.w += fmaxf(f0[3] + h0.w, 0.f) + fmaxf(f1[3] + h1.w, 0.f);
    }
    for (; p < pEnd; p += 2) {
        int2 ea = eids2[p];
        f32x4 f0 = __builtin_nontemporal_load(
            reinterpret_cast<const f32x4*>(&ef[(size_t)ea.x * D + c * 4]));
        float4 h0 = bf4_to_f4(*reinterpret_cast<const ushort4*>(&hp[(size_t)ea.y * D + c * 4]));
        acc.x += fmaxf(f0[0] + h0.x, 0.f);
        acc.y += fmaxf(f0[1] + h0.y, 0.f);
        acc.z += fmaxf(f0[2] + h0.z, 0.f);
        acc.w += fmaxf(f0[3] + h0.w, 0.f);
    }
    // combine the two half-wave partials
    acc.x += __shfl_xor(acc.x, 32, 64);
    acc.y += __shfl_xor(acc.y, 32, 64);
    acc.z += __shfl_xor(acc.z, 32, 64);
    acc.w += __shfl_xor(acc.w, 32, 64);
    if (eh == 0) {
        ushort4 o;
        o.x = f2bf(h.x + acc.x);
        o.y = f2bf(h.y + acc.y);
        o.z = f2bf(h.z + acc.z);
        o.w = f2bf(h.w + acc.w);
        *reinterpret_cast<ushort4*>(&zb[(size_t)node * D + c * 4]) = o;
    }
}

// ---------------------------------------------------------------- 5. pack weights into MFMA fragment order
__global__ __launch_bounds__(256) void pack_w_kernel(
    const float* __restrict__ W1, const float* __restrict__ W2,
    ushort* __restrict__ w1p, ushort* __restrict__ w2p) {
    int idx = blockIdx.x * 256 + threadIdx.x;
    if (idx >= 32768) return;
    {
        int j = idx & 7, l = (idx >> 3) & 63, nb = (idx >> 9) & 15, kb = idx >> 13;
        int k = kb * 32 + (l >> 4) * 8 + j, n = nb * 16 + (l & 15);
        w1p[idx] = f2bf(W1[k * DH + n]);
    }
    {
        int j = idx & 7, l = (idx >> 3) & 63, nb = (idx >> 9) & 7, kb = idx >> 12;
        int k = kb * 32 + (l >> 4) * 8 + j, n = nb * 16 + (l & 15);
        w2p[idx] = f2bf(W2[k * DUP + n]);
    }
}

// ---------------------------------------------------------------- 6. MFMA MLP: 64 nodes/block, 16/wave
__global__ __launch_bounds__(256) void mlp_mfma_kernel(
    const ushort* __restrict__ zb,
    const ushort* __restrict__ w1p, const float* __restrict__ b1,
    const ushort* __restrict__ w2p, const float* __restrict__ b2,
    float* __restrict__ out, int N) {
    __shared__ ushort u_lds[4][16][DH + 8];
    const int tid = threadIdx.x;
    const int wave = tid >> 6, lane = tid & 63;
    const int m0 = blockIdx.x * 64 + wave * 16;
    const int lr = lane & 15, lg = lane >> 4;

    bf16x8 a1[4];
    int rowA = m0 + lr; if (rowA > N - 1) rowA = N - 1;
    const ushort* zrow = &zb[(size_t)rowA * D + lg * 8];
#pragma unroll
    for (int kb = 0; kb < 4; ++kb)
        a1[kb] = *reinterpret_cast<const bf16x8*>(zrow + kb * 32);

#pragma unroll
    for (int nb = 0; nb < 16; ++nb) {
        f32x4 c = {0.f, 0.f, 0.f, 0.f};
#pragma unroll
        for (int kb = 0; kb < 4; ++kb) {
            bf16x8 b = *reinterpret_cast<const bf16x8*>(&w1p[((kb * 16 + nb) * 64 + lane) * 8]);
            c = __builtin_amdgcn_mfma_f32_16x16x32_bf16(a1[kb], b, c, 0, 0, 0);
        }
        float bias = b1[nb * 16 + lr];
#pragma unroll
        for (int r = 0; r < 4; ++r) {
            float v = fmaxf(c[r] + bias, 0.f);
            u_lds[wave][lg * 4 + r][nb * 16 + lr] = f2bf(v);
        }
    }
    __syncthreads();

    bf16x8 a2[8];
#pragma unroll
    for (int kb = 0; kb < 8; ++kb)
        a2[kb] = *reinterpret_cast<const bf16x8*>(&u_lds[wave][lr][kb * 32 + lg * 8]);

#pragma unroll
    for (int nb = 0; nb < 8; ++nb) {
        f32x4 c = {0.f, 0.f, 0.f, 0.f};
#pragma unroll
        for (int kb = 0; kb < 8; ++kb) {
            bf16x8 b = *reinterpret_cast<const bf16x8*>(&w2p[((kb * 8 + nb) * 64 + lane) * 8]);
            c = __builtin_amdgcn_mfma_f32_16x16x32_bf16(a2[kb], b, c, 0, 0, 0);
        }
        float bias = b2[nb * 16 + lr];
#pragma unroll
        for (int r = 0; r < 4; ++r) {
            int row = m0 + lg * 4 + r;
            if (row < N) out[(size_t)row * DUP + nb * 16 + lr] = c[r] + bias;
        }
    }
}

// ---------------------------------------------------------------- launch
extern "C" void kernel_launch(void* const* d_in, const int* in_sizes, int n_in,
                              void* d_out, int out_size, void* d_ws, size_t ws_size,
                              hipStream_t stream) {
    const float* x   = (const float*)d_in[0];
    const float* dg  = (const float*)d_in[1];
    const float* ef  = (const float*)d_in[2];
    const float* W1  = (const float*)d_in[3];
    const float* b1  = (const float*)d_in[4];
    const float* W2  = (const float*)d_in[5];
    const float* b2  = (const float*)d_in[6];
    const int*   ei  = (const int*)d_in[7];
    float* out = (float*)d_out;

    const int N = in_sizes[0] / DIN;       // 50000
    const int E = in_sizes[7] / 2;         // 800000

    auto align16 = [](size_t v) { return (v + 15) & ~(size_t)15; };
    char* w = (char*)d_ws;
    ushort* zb      = (ushort*)w;  w += align16((size_t)N * D * 2);
    ushort* hp      = (ushort*)w;  w += align16((size_t)N * D * 2);
    int*   counts   = (int*)w;     w += align16((size_t)N * 4);
    int*   offsets  = (int*)w;     w += align16((size_t)(N + 1) * 4);
    int*   cursor   = (int*)w;     w += align16((size_t)N * 4);
    int2*  eids2    = (int2*)w;    w += align16((size_t)E * 8);
    int*   blockSums= (int*)w;     w += align16(64 * 4);
    int*   blockBase= (int*)w;     w += align16(64 * 4);
    ushort* w1p     = (ushort*)w;  w += align16((size_t)D * DH * 2);
    ushort* w2p     = (ushort*)w;  w += align16((size_t)DH * DUP * 2);

    hipMemsetAsync(counts, 0, (size_t)N * 4, stream);

    const int eb = (E + 255) / 256;
    const int nbScan = (N + 1023) / 1024;   // 49

    init_h_kernel<<<(N * 32 + 255) / 256, 256, 0, stream>>>(x, dg, hp, N);
    count_kernel<<<eb, 256, 0, stream>>>(ei, counts, N, E);
    scan_partial_kernel<<<nbScan, 256, 0, stream>>>(counts, blockSums, N);
    scan_base_kernel<<<1, 64, 0, stream>>>(blockSums, blockBase, nbScan);
    scan_final_kernel<<<nbScan, 256, 0, stream>>>(counts, blockBase, offsets, cursor, N, E);
    fill_kernel<<<eb, 256, 0, stream>>>(ei, cursor, eids2, E);

    gather_kernel<<<(N + 3) / 4, 256, 0, stream>>>(hp, ef, offsets, eids2, zb, N);

    pack_w_kernel<<<128, 256, 0, stream>>>(W1, W2, w1p, w2p);
    mlp_mfma_kernel<<<(N + 63) / 64, 256, 0, stream>>>(zb, w1p, b1, w2p, b2, out, N);
}

// Round 5
// 242.713 us; speedup vs baseline: 6.3265x; 1.0266x over previous
//
#include <hip/hip_runtime.h>

// MPNN_edge_sparse_ogb — round 4:
//  - gather v3: half-wave per node, 4-wide unroll (8 vector loads in flight),
//    broadcast id loads; counts zeroing folded into init_h (one less dispatch).
// ws: zb[N*128]bf16 | hp[N*128]bf16 | counts | offsets | cursor | eids2[E]int2 | sums | w1p | w2p

constexpr int DIN  = 96;
constexpr int DDEG = 32;
constexpr int D    = 128;
constexpr int DH   = 256;
constexpr int DUP  = 128;

typedef short bf16x8 __attribute__((ext_vector_type(8)));
typedef float f32x4  __attribute__((ext_vector_type(4)));

static __device__ __forceinline__ ushort f2bf(float f) {
    unsigned u = __float_as_uint(f);
    unsigned r = (u + 0x7fff + ((u >> 16) & 1)) >> 16;   // RNE
    return (ushort)r;
}
static __device__ __forceinline__ float4 bf4_to_f4(ushort4 u) {
    float4 r;
    r.x = __uint_as_float((unsigned)u.x << 16);
    r.y = __uint_as_float((unsigned)u.y << 16);
    r.z = __uint_as_float((unsigned)u.z << 16);
    r.w = __uint_as_float((unsigned)u.w << 16);
    return r;
}

static __device__ __forceinline__ int waveInclScan(int v, int lane) {
#pragma unroll
    for (int off = 1; off < 64; off <<= 1) {
        int t = __shfl_up(v, off, 64);
        if (lane >= off) v += t;
    }
    return v;
}

// ---------------------------------------------------------------- 0. pack h = bf16(concat(x,deg)) + zero counts
__global__ __launch_bounds__(256) void init_h_kernel(
    const float* __restrict__ x, const float* __restrict__ deg,
    ushort* __restrict__ hp, int* __restrict__ counts, int N) {
    int t = blockIdx.x * 256 + threadIdx.x;
    if (t < (N >> 2)) *reinterpret_cast<int4*>(&counts[t * 4]) = make_int4(0, 0, 0, 0);
    if (t == (N >> 2) && (N & 3)) {
        for (int i = (N & ~3); i < N; ++i) counts[i] = 0;
    }
    if (t >= N * 32) return;
    int n = t >> 5, c = t & 31;
    float4 v;
    if (c < 24) v = *reinterpret_cast<const float4*>(&x[(size_t)n * DIN + c * 4]);
    else        v = *reinterpret_cast<const float4*>(&deg[(size_t)n * DDEG + (c - 24) * 4]);
    ushort4 o;
    o.x = f2bf(v.x); o.y = f2bf(v.y); o.z = f2bf(v.z); o.w = f2bf(v.w);
    *reinterpret_cast<ushort4*>(&hp[(size_t)n * D + c * 4]) = o;
}

// ---------------------------------------------------------------- 1. count in-degrees
__global__ __launch_bounds__(256) void count_kernel(
    const int* __restrict__ ei, int* __restrict__ counts, int N, int E) {
    int e = blockIdx.x * 256 + threadIdx.x;
    if (e >= E) return;
    atomicAdd(&counts[ei[E + e]], 1);
}

// ---------------------------------------------------------------- 2a. per-1024-block sums
__global__ __launch_bounds__(256) void scan_partial_kernel(
    const int* __restrict__ counts, int* __restrict__ blockSums, int N) {
    const int tid = threadIdx.x;
    int base = blockIdx.x * 1024 + tid * 4;
    int4 c = make_int4(0, 0, 0, 0);
    if (base + 3 < N) c = *reinterpret_cast<const int4*>(&counts[base]);
    else if (base < N) {
        c.x = counts[base];
        if (base + 1 < N) c.y = counts[base + 1];
        if (base + 2 < N) c.z = counts[base + 2];
    }
    int s = c.x + c.y + c.z + c.w;
#pragma unroll
    for (int off = 32; off; off >>= 1) s += __shfl_xor(s, off, 64);
    __shared__ int wsum[4];
    if ((tid & 63) == 0) wsum[tid >> 6] = s;
    __syncthreads();
    if (tid == 0) blockSums[blockIdx.x] = wsum[0] + wsum[1] + wsum[2] + wsum[3];
}

// ---------------------------------------------------------------- 2b. scan block sums (<=64)
__global__ __launch_bounds__(64) void scan_base_kernel(
    const int* __restrict__ blockSums, int* __restrict__ blockBase, int nb) {
    int l = threadIdx.x;
    int orig = (l < nb) ? blockSums[l] : 0;
    int incl = waveInclScan(orig, l);
    if (l < nb) blockBase[l] = incl - orig;
}

// ---------------------------------------------------------------- 2c. final scan -> offsets/cursor
__global__ __launch_bounds__(256) void scan_final_kernel(
    const int* __restrict__ counts, const int* __restrict__ blockBase,
    int* __restrict__ offsets, int* __restrict__ cursor, int N, int E) {
    const int tid = threadIdx.x, lane = tid & 63, wave = tid >> 6;
    int base = blockIdx.x * 1024 + tid * 4;
    int4 c = make_int4(0, 0, 0, 0);
    if (base + 3 < N) c = *reinterpret_cast<const int4*>(&counts[base]);
    else if (base < N) {
        c.x = counts[base];
        if (base + 1 < N) c.y = counts[base + 1];
        if (base + 2 < N) c.z = counts[base + 2];
    }
    int s = c.x + c.y + c.z + c.w;
    int incl = waveInclScan(s, lane);
    __shared__ int wsum[4];
    if (lane == 63) wsum[wave] = incl;
    __syncthreads();
    int wb = 0;
#pragma unroll
    for (int w = 0; w < 4; ++w)
        if (w < wave) wb += wsum[w];
    int ex = blockBase[blockIdx.x] + wb + (incl - s);
    if (base < N)     { offsets[base]     = ex; cursor[base]     = ex; } ex += c.x;
    if (base + 1 < N) { offsets[base + 1] = ex; cursor[base + 1] = ex; } ex += c.y;
    if (base + 2 < N) { offsets[base + 2] = ex; cursor[base + 2] = ex; } ex += c.z;
    if (base + 3 < N) { offsets[base + 3] = ex; cursor[base + 3] = ex; }
    if (blockIdx.x == 0 && tid == 0) offsets[N] = E;
}

// ---------------------------------------------------------------- 3. fill CSR payload {e, src}
__global__ __launch_bounds__(256) void fill_kernel(
    const int* __restrict__ ei, int* __restrict__ cursor,
    int2* __restrict__ eids2, int E) {
    int e = blockIdx.x * 256 + threadIdx.x;
    if (e >= E) return;
    int src = ei[e];
    int dst = ei[E + e];
    int pos = atomicAdd(&cursor[dst], 1);
    eids2[pos] = make_int2(e, src);
}

// ---------------------------------------------------------------- 4. gather: zb = bf16(h + sum relu(h[src]+ef))
// half-wave per node; 4-wide unroll = 8 vector loads in flight per half-wave.
__global__ __launch_bounds__(256) void gather_kernel(
    const ushort* __restrict__ hp, const float* __restrict__ ef,
    const int* __restrict__ offsets, const int2* __restrict__ eids2,
    ushort* __restrict__ zb, int N) {
    const int node = blockIdx.x * 8 + (threadIdx.x >> 5);
    if (node >= N) return;
    const int c = threadIdx.x & 31;   // float4 chunk 0..31

    float4 h = bf4_to_f4(*reinterpret_cast<const ushort4*>(&hp[(size_t)node * D + c * 4]));

    float4 acc = make_float4(0.f, 0.f, 0.f, 0.f);
    const int pEnd = offsets[node + 1];
    int p = offsets[node];

    for (; p + 4 <= pEnd; p += 4) {
        int2 i0 = eids2[p + 0];
        int2 i1 = eids2[p + 1];
        int2 i2 = eids2[p + 2];
        int2 i3 = eids2[p + 3];
        f32x4 f0 = __builtin_nontemporal_load(
            reinterpret_cast<const f32x4*>(&ef[(size_t)i0.x * D + c * 4]));
        f32x4 f1 = __builtin_nontemporal_load(
            reinterpret_cast<const f32x4*>(&ef[(size_t)i1.x * D + c * 4]));
        f32x4 f2 = __builtin_nontemporal_load(
            reinterpret_cast<const f32x4*>(&ef[(size_t)i2.x * D + c * 4]));
        f32x4 f3 = __builtin_nontemporal_load(
            reinterpret_cast<const f32x4*>(&ef[(size_t)i3.x * D + c * 4]));
        float4 h0 = bf4_to_f4(*reinterpret_cast<const ushort4*>(&hp[(size_t)i0.y * D + c * 4]));
        float4 h1 = bf4_to_f4(*reinterpret_cast<const ushort4*>(&hp[(size_t)i1.y * D + c * 4]));
        float4 h2 = bf4_to_f4(*reinterpret_cast<const ushort4*>(&hp[(size_t)i2.y * D + c * 4]));
        float4 h3 = bf4_to_f4(*reinterpret_cast<const ushort4*>(&hp[(size_t)i3.y * D + c * 4]));
        acc.x += fmaxf(f0[0] + h0.x, 0.f) + fmaxf(f1[0] + h1.x, 0.f)
               + fmaxf(f2[0] + h2.x, 0.f) + fmaxf(f3[0] + h3.x, 0.f);
        acc.y += fmaxf(f0[1] + h0.y, 0.f) + fmaxf(f1[1] + h1.y, 0.f)
               + fmaxf(f2[1] + h2.y, 0.f) + fmaxf(f3[1] + h3.y, 0.f);
        acc.z += fmaxf(f0[2] + h0.z, 0.f) + fmaxf(f1[2] + h1.z, 0.f)
               + fmaxf(f2[2] + h2.z, 0.f) + fmaxf(f3[2] + h3.z, 0.f);
        acc.w += fmaxf(f0[3] + h0.w, 0.f) + fmaxf(f1[3] + h1.w, 0.f)
               + fmaxf(f2[3] + h2.w, 0.f) + fmaxf(f3[3] + h3.w, 0.f);
    }
    for (; p < pEnd; ++p) {
        int2 i0 = eids2[p];
        f32x4 f0 = __builtin_nontemporal_load(
            reinterpret_cast<const f32x4*>(&ef[(size_t)i0.x * D + c * 4]));
        float4 h0 = bf4_to_f4(*reinterpret_cast<const ushort4*>(&hp[(size_t)i0.y * D + c * 4]));
        acc.x += fmaxf(f0[0] + h0.x, 0.f);
        acc.y += fmaxf(f0[1] + h0.y, 0.f);
        acc.z += fmaxf(f0[2] + h0.z, 0.f);
        acc.w += fmaxf(f0[3] + h0.w, 0.f);
    }
    ushort4 o;
    o.x = f2bf(h.x + acc.x);
    o.y = f2bf(h.y + acc.y);
    o.z = f2bf(h.z + acc.z);
    o.w = f2bf(h.w + acc.w);
    *reinterpret_cast<ushort4*>(&zb[(size_t)node * D + c * 4]) = o;
}

// ---------------------------------------------------------------- 5. pack weights into MFMA fragment order
__global__ __launch_bounds__(256) void pack_w_kernel(
    const float* __restrict__ W1, const float* __restrict__ W2,
    ushort* __restrict__ w1p, ushort* __restrict__ w2p) {
    int idx = blockIdx.x * 256 + threadIdx.x;
    if (idx >= 32768) return;
    {
        int j = idx & 7, l = (idx >> 3) & 63, nb = (idx >> 9) & 15, kb = idx >> 13;
        int k = kb * 32 + (l >> 4) * 8 + j, n = nb * 16 + (l & 15);
        w1p[idx] = f2bf(W1[k * DH + n]);
    }
    {
        int j = idx & 7, l = (idx >> 3) & 63, nb = (idx >> 9) & 7, kb = idx >> 12;
        int k = kb * 32 + (l >> 4) * 8 + j, n = nb * 16 + (l & 15);
        w2p[idx] = f2bf(W2[k * DUP + n]);
    }
}

// ---------------------------------------------------------------- 6. MFMA MLP: 64 nodes/block, 16/wave
__global__ __launch_bounds__(256) void mlp_mfma_kernel(
    const ushort* __restrict__ zb,
    const ushort* __restrict__ w1p, const float* __restrict__ b1,
    const ushort* __restrict__ w2p, const float* __restrict__ b2,
    float* __restrict__ out, int N) {
    __shared__ ushort u_lds[4][16][DH + 8];
    const int tid = threadIdx.x;
    const int wave = tid >> 6, lane = tid & 63;
    const int m0 = blockIdx.x * 64 + wave * 16;
    const int lr = lane & 15, lg = lane >> 4;

    bf16x8 a1[4];
    int rowA = m0 + lr; if (rowA > N - 1) rowA = N - 1;
    const ushort* zrow = &zb[(size_t)rowA * D + lg * 8];
#pragma unroll
    for (int kb = 0; kb < 4; ++kb)
        a1[kb] = *reinterpret_cast<const bf16x8*>(zrow + kb * 32);

#pragma unroll
    for (int nb = 0; nb < 16; ++nb) {
        f32x4 c = {0.f, 0.f, 0.f, 0.f};
#pragma unroll
        for (int kb = 0; kb < 4; ++kb) {
            bf16x8 b = *reinterpret_cast<const bf16x8*>(&w1p[((kb * 16 + nb) * 64 + lane) * 8]);
            c = __builtin_amdgcn_mfma_f32_16x16x32_bf16(a1[kb], b, c, 0, 0, 0);
        }
        float bias = b1[nb * 16 + lr];
#pragma unroll
        for (int r = 0; r < 4; ++r) {
            float v = fmaxf(c[r] + bias, 0.f);
            u_lds[wave][lg * 4 + r][nb * 16 + lr] = f2bf(v);
        }
    }
    __syncthreads();

    bf16x8 a2[8];
#pragma unroll
    for (int kb = 0; kb < 8; ++kb)
        a2[kb] = *reinterpret_cast<const bf16x8*>(&u_lds[wave][lr][kb * 32 + lg * 8]);

#pragma unroll
    for (int nb = 0; nb < 8; ++nb) {
        f32x4 c = {0.f, 0.f, 0.f, 0.f};
#pragma unroll
        for (int kb = 0; kb < 8; ++kb) {
            bf16x8 b = *reinterpret_cast<const bf16x8*>(&w2p[((kb * 8 + nb) * 64 + lane) * 8]);
            c = __builtin_amdgcn_mfma_f32_16x16x32_bf16(a2[kb], b, c, 0, 0, 0);
        }
        float bias = b2[nb * 16 + lr];
#pragma unroll
        for (int r = 0; r < 4; ++r) {
            int row = m0 + lg * 4 + r;
            if (row < N) out[(size_t)row * DUP + nb * 16 + lr] = c[r] + bias;
        }
    }
}

// ---------------------------------------------------------------- launch
extern "C" void kernel_launch(void* const* d_in, const int* in_sizes, int n_in,
                              void* d_out, int out_size, void* d_ws, size_t ws_size,
                              hipStream_t stream) {
    const float* x   = (const float*)d_in[0];
    const float* dg  = (const float*)d_in[1];
    const float* ef  = (const float*)d_in[2];
    const float* W1  = (const float*)d_in[3];
    const float* b1  = (const float*)d_in[4];
    const float* W2  = (const float*)d_in[5];
    const float* b2  = (const float*)d_in[6];
    const int*   ei  = (const int*)d_in[7];
    float* out = (float*)d_out;

    const int N = in_sizes[0] / DIN;       // 50000
    const int E = in_sizes[7] / 2;         // 800000

    auto align16 = [](size_t v) { return (v + 15) & ~(size_t)15; };
    char* w = (char*)d_ws;
    ushort* zb      = (ushort*)w;  w += align16((size_t)N * D * 2);
    ushort* hp      = (ushort*)w;  w += align16((size_t)N * D * 2);
    int*   counts   = (int*)w;     w += align16((size_t)N * 4);
    int*   offsets  = (int*)w;     w += align16((size_t)(N + 1) * 4);
    int*   cursor   = (int*)w;     w += align16((size_t)N * 4);
    int2*  eids2    = (int2*)w;    w += align16((size_t)E * 8);
    int*   blockSums= (int*)w;     w += align16(64 * 4);
    int*   blockBase= (int*)w;     w += align16(64 * 4);
    ushort* w1p     = (ushort*)w;  w += align16((size_t)D * DH * 2);
    ushort* w2p     = (ushort*)w;  w += align16((size_t)DH * DUP * 2);

    const int eb = (E + 255) / 256;
    const int nbScan = (N + 1023) / 1024;   // 49

    init_h_kernel<<<(N * 32 + 255) / 256, 256, 0, stream>>>(x, dg, hp, counts, N);
    count_kernel<<<eb, 256, 0, stream>>>(ei, counts, N, E);
    scan_partial_kernel<<<nbScan, 256, 0, stream>>>(counts, blockSums, N);
    scan_base_kernel<<<1, 64, 0, stream>>>(blockSums, blockBase, nbScan);
    scan_final_kernel<<<nbScan, 256, 0, stream>>>(counts, blockBase, offsets, cursor, N, E);
    fill_kernel<<<eb, 256, 0, stream>>>(ei, cursor, eids2, E);

    gather_kernel<<<(N + 7) / 8, 256, 0, stream>>>(hp, ef, offsets, eids2, zb, N);

    pack_w_kernel<<<128, 256, 0, stream>>>(W1, W2, w1p, w2p);
    mlp_mfma_kernel<<<(N + 63) / 64, 256, 0, stream>>>(zb, w1p, b1, w2p, b2, out, N);
}